// Round 9
// baseline (630.139 us; speedup 1.0000x reference)
//
#include <hip/hip_runtime.h>
#include <math.h>

#define L_LEN 4500
#define T2 128
#define NT2 36    // ceil(4500/128)
#define CKSPL 12  // l-splits for corr_k
#define NT64 71   // ceil(4500/64)

// ---------------- prep: transpose conv2 weights to [cin][g][k] ----------------
__global__ void prep_w2t_k(const float* __restrict__ w2, float* __restrict__ w2t) {
    int i = blockIdx.x * 256 + threadIdx.x;
    if (i < 64 * 64 * 5) {
        int k = i / 320;
        int r = i - k * 320;
        int c = r / 5;
        int g = r - c * 5;
        w2t[(c * 5 + g) * 64 + k] = w2[i];
    }
}

// ---- conv12_k: fused conv1 (k=7) + conv2 (k=5) : x -> h2; + sq/rowsum stats --
__global__ __launch_bounds__(256) void conv12_k(const float* __restrict__ x,
                                                const float* __restrict__ w1,
                                                const float* __restrict__ w2t,
                                                float* __restrict__ h2,
                                                float* __restrict__ sq,
                                                float* __restrict__ rowsum) {
    __shared__ float xs[144];
    __shared__ __align__(16) float h1s[64 * 132];
    int n = blockIdx.x / NT2;
    int t = blockIdx.x - n * NT2;
    int l0 = t * T2;
    const float* xr = x + (size_t)n * L_LEN;
    if (threadIdx.x < 138) {
        int l = l0 - 5 + threadIdx.x;
        xs[threadIdx.x] = (l >= 0 && l < L_LEN) ? xr[l] : 0.f;
    }
    __syncthreads();
    {
        int vci = threadIdx.x >> 2;
        int seg = threadIdx.x & 3;
        int j0 = seg * 33;
        float w[7];
#pragma unroll
        for (int g = 0; g < 7; ++g) w[g] = w1[vci * 7 + g];
        for (int jj = 0; jj < 33; ++jj) {
            int j = j0 + jj;
            int l = l0 - 2 + j;
            float a = 0.f;
#pragma unroll
            for (int g = 0; g < 7; ++g) a += w[g] * xs[j + g];
            h1s[vci * 132 + j] = (l >= 0 && l < L_LEN) ? a : 0.f;   // SAME-pad zeroing
        }
    }
    __syncthreads();
    int ta = threadIdx.x & 15;
    int tb = threadIdx.x >> 4;
    int k0 = ta * 4;
    int lt = tb * 8;
    float acc[4][8];
#pragma unroll
    for (int kq = 0; kq < 4; ++kq)
#pragma unroll
        for (int m = 0; m < 8; ++m) acc[kq][m] = 0.f;
    for (int ci = 0; ci < 64; ++ci) {
        const float* hrow = &h1s[ci * 132 + lt];
        float4 wa = *(const float4*)hrow;
        float4 wb = *(const float4*)(hrow + 4);
        float4 wc = *(const float4*)(hrow + 8);
        float win[12] = {wa.x, wa.y, wa.z, wa.w, wb.x, wb.y, wb.z, wb.w,
                         wc.x, wc.y, wc.z, wc.w};
        const float* wp = w2t + ci * 320 + k0;
#pragma unroll
        for (int g = 0; g < 5; ++g) {
            float4 wv = *(const float4*)(wp + g * 64);
#pragma unroll
            for (int m = 0; m < 8; ++m) {
                acc[0][m] += wv.x * win[m + g];
                acc[1][m] += wv.y * win[m + g];
                acc[2][m] += wv.z * win[m + g];
                acc[3][m] += wv.w * win[m + g];
            }
        }
    }
    int lbase = l0 + lt;
#pragma unroll
    for (int kq = 0; kq < 4; ++kq) {
        float* orow = h2 + ((size_t)n * 64 + k0 + kq) * L_LEN + lbase;
        if (lbase < L_LEN) {
            float4 s0 = {acc[kq][0], acc[kq][1], acc[kq][2], acc[kq][3]};
            *(float4*)orow = s0;
        }
        if (lbase + 4 < L_LEN) {
            float4 s1 = {acc[kq][4], acc[kq][5], acc[kq][6], acc[kq][7]};
            *(float4*)(orow + 4) = s1;
        }
    }
    // ---- fused per-(n,k) sum / sumsq (h1s dead -> reuse as reduce scratch) ----
    __syncthreads();
    float* sqs = h1s;          // [64][16]
    float* rss = h1s + 1024;   // [64][16]
#pragma unroll
    for (int kq = 0; kq < 4; ++kq) {
        float sqp = 0.f, rsp = 0.f;
#pragma unroll
        for (int m = 0; m < 8; ++m) {
            if (lbase + m < L_LEN) { float v = acc[kq][m]; sqp += v * v; rsp += v; }
        }
        sqs[(k0 + kq) * 16 + tb] = sqp;
        rss[(k0 + kq) * 16 + tb] = rsp;
    }
    __syncthreads();
    if (threadIdx.x < 64) {
        float s = 0.f, r = 0.f;
#pragma unroll
        for (int q = 0; q < 16; ++q) {
            s += sqs[threadIdx.x * 16 + q];
            r += rss[threadIdx.x * 16 + q];
        }
        atomicAdd(&sq[n * 64 + threadIdx.x], s);
        atomicAdd(&rowsum[n * 64 + threadIdx.x], r);
    }
}

// ---- corr_k: R[a][b][d] = sum_l h2[a][l]*h2[b][l+d-2]  (raw h2, OOB=0) ------
// ph splits b-range (tb 0-7 / 8-15): grid 2x for occupancy; waves 0-1 vs 2-3
// cover alternating l-chunks (wave-uniform parity), folded in-block via hsT.
// Partial layout in Rp is IDENTICAL to round-8 (ph blocks fill disjoint tth).
__global__ __launch_bounds__(256) void corr_k(const float* __restrict__ h2,
                                              float* __restrict__ Rp) {
    __shared__ __align__(16) float hsT[5312];   // staging 72*68=4896; fold 64*83=5312
    int bx = blockIdx.x;
    int n = bx / (2 * CKSPL);
    int r = bx - n * (2 * CKSPL);
    int s = r % CKSPL;
    int ph = r / CKSPL;
    int tid = threadIdx.x;
    int half = tid >> 7;           // wave-uniform (waves 0-1: 0, waves 2-3: 1)
    int tIdx = tid & 127;
    int ta = tIdx & 15;
    int tb = ph * 8 + (tIdx >> 4);
    const float* h2n = h2 + (size_t)n * 64 * L_LEN;
    float acc[80];   // acc[ar*20 + br*5 + d]
#pragma unroll
    for (int e = 0; e < 80; ++e) acc[e] = 0.f;
    int as = tid >> 6;
    int jl = tid & 63;
    int j2 = 64 + (tid & 7);
    int a2 = tid >> 3;   // 0..31

    int q = 0;
    for (int t = s; t < NT64; t += CKSPL, ++q) {
        int l0 = t * 64;
        __syncthreads();
        {
            int l = l0 + jl - 4;
            bool ok = (l >= 0 && l < L_LEN);
#pragma unroll
            for (int ait = 0; ait < 16; ++ait) {
                int a = as * 16 + ait;
                hsT[jl * 68 + a] = ok ? h2n[(size_t)a * L_LEN + l] : 0.f;
            }
        }
        {
            int l = l0 + j2 - 4;
            bool ok = (l >= 0 && l < L_LEN);
            hsT[j2 * 68 + a2] = ok ? h2n[(size_t)a2 * L_LEN + l] : 0.f;
            hsT[j2 * 68 + a2 + 32] = ok ? h2n[(size_t)(a2 + 32) * L_LEN + l] : 0.f;
        }
        __syncthreads();
        if ((q & 1) == half) {     // wave-uniform: skipped waves cost no VALU
            for (int lk = 0; lk < 16; ++lk) {
                float aw[4][4], bw[8][4];
#pragma unroll
                for (int m = 0; m < 4; ++m) {
                    float4 v = *(const float4*)&hsT[(lk * 4 + 4 + m) * 68 + ta * 4];
                    aw[m][0] = v.x; aw[m][1] = v.y; aw[m][2] = v.z; aw[m][3] = v.w;
                }
#pragma unroll
                for (int qq = 0; qq < 8; ++qq) {
                    float4 v = *(const float4*)&hsT[(lk * 4 + 2 + qq) * 68 + tb * 4];
                    bw[qq][0] = v.x; bw[qq][1] = v.y; bw[qq][2] = v.z; bw[qq][3] = v.w;
                }
#pragma unroll
                for (int m = 0; m < 4; ++m)
#pragma unroll
                    for (int d = 0; d < 5; ++d)
#pragma unroll
                        for (int ar = 0; ar < 4; ++ar)
#pragma unroll
                            for (int br = 0; br < 4; ++br)
                                acc[ar * 20 + br * 5 + d] += aw[m][ar] * bw[m + d][br];
            }
        }
    }
    // ---- fold half1 (tids 128..255) into half0 partner (tid-128) via hsT ----
    __syncthreads();
    if (tid >= 128 && tid < 192) {
#pragma unroll
        for (int e = 0; e < 80; ++e) hsT[(tid - 128) * 83 + e] = acc[e];
    }
    __syncthreads();
    if (tid < 64) {
#pragma unroll
        for (int e = 0; e < 80; ++e) acc[e] += hsT[tid * 83 + e];
    }
    __syncthreads();
    if (tid >= 192) {
#pragma unroll
        for (int e = 0; e < 80; ++e) hsT[(tid - 192) * 83 + e] = acc[e];
    }
    __syncthreads();
    if (tid >= 64 && tid < 128) {
#pragma unroll
        for (int e = 0; e < 80; ++e) acc[e] += hsT[(tid - 64) * 83 + e];
    }
    if (tid < 128) {
        int tth = ta + tb * 16;    // disjoint across ph blocks
        float* base = Rp + (size_t)(n * CKSPL + s) * 20480 + tth * 4;
#pragma unroll
        for (int e4 = 0; e4 < 20; ++e4) {
            float4 w4 = {acc[e4 * 4], acc[e4 * 4 + 1], acc[e4 * 4 + 2], acc[e4 * 4 + 3]};
            *(float4*)(base + e4 * 1024) = w4;
        }
    }
}

// ---------- reduce_k: element-wise sum of the CKSPL partials -----------------
__global__ __launch_bounds__(256) void reduce_k(const float* __restrict__ Rp,
                                                float* __restrict__ Rsum) {
    int n = blockIdx.x / 80;
    int bb = blockIdx.x - n * 80;
    int idx = bb * 256 + threadIdx.x;
    float s = 0.f;
#pragma unroll
    for (int s2 = 0; s2 < CKSPL; ++s2) s += Rp[((size_t)n * CKSPL + s2) * 20480 + idx];
    Rsum[(size_t)n * 20480 + idx] = s;
}

// ---- massemble_k: one (n, i, j) per block -> Mfull[n][c][ij] ----------------
__global__ __launch_bounds__(256) void massemble_k(const float* __restrict__ Rsum,
                                                   const float* __restrict__ h2,
                                                   const float* __restrict__ sq,
                                                   const float* __restrict__ wA,
                                                   float* __restrict__ Mfull) {
    __shared__ float Rsub[320];
    __shared__ float s0s[64], s1s[64], invs[64];
    __shared__ float Mred[256];
    int n = blockIdx.x / 36;
    int ij = blockIdx.x - n * 36;
    int i = 0, rem = ij;
    while (rem >= 8 - i) { rem -= 8 - i; ++i; }
    int j = i + rem;
    int c = threadIdx.x & 63;
    int sub = threadIdx.x >> 6;
    if (threadIdx.x < 64) {
        int a = threadIdx.x;
        s0s[a] = h2[((size_t)n * 64 + a) * L_LEN + 0];
        s1s[a] = h2[((size_t)n * 64 + a) * L_LEN + (L_LEN - 1)];
        invs[a] = 1.f / (1.f + sq[n * 64 + a]);
    }
    for (int fidx = threadIdx.x; fidx < 320; fidx += 256) {
        int p = fidx / 40;
        int rr = fidx - 40 * p;
        int pp = rr / 5;
        int d = rr - 5 * pp;
        int a = 8 * i + p, b = 8 * j + pp;
        int tth = (a >> 2) + ((b >> 2) << 4);
        int flat = (((a & 3) << 2) + (b & 3)) * 5 + d;
        Rsub[fidx] = Rsum[(size_t)n * 20480 + (flat >> 2) * 1024 + tth * 4 + (flat & 3)];
    }
    float wreg[24];
#pragma unroll
    for (int q = 0; q < 24; ++q) wreg[q] = wA[c * 24 + q];
    __syncthreads();
    float acc = 0.f;
#pragma unroll
    for (int pl = 0; pl < 2; ++pl) {
        int p = sub * 2 + pl;
        int a = 8 * i + p;
        float ia = invs[a];
        float w0 = wreg[p * 3], w1 = wreg[p * 3 + 1], w2v = wreg[p * 3 + 2];
        float e1a = s1s[a], e0a = s0s[a];
#pragma unroll
        for (int pp = 0; pp < 8; ++pp) {
            int b = 8 * j + pp;
            float q0 = wreg[pp * 3], q1 = wreg[pp * 3 + 1], q2 = wreg[pp * 3 + 2];
            const float* R5 = &Rsub[(p * 8 + pp) * 5];
            float term = (w2v * q0) * R5[0]
                       + (w1 * q0 + w2v * q1) * R5[1]
                       + (w0 * q0 + w1 * q1 + w2v * q2) * R5[2]
                       + (w0 * q1 + w1 * q2) * R5[3]
                       + (w0 * q2) * R5[4]
                       - (w0 * q0) * (e1a * s1s[b])
                       - (w2v * q2) * (e0a * s0s[b]);
            acc += ia * invs[b] * term;
        }
    }
    Mred[sub * 64 + c] = acc;
    __syncthreads();
    if (sub == 0)
        Mfull[((size_t)n * 64 + c) * 36 + ij] =
            Mred[c] + Mred[64 + c] + Mred[128 + c] + Mred[192 + c];
}

// ---- routing_k: M + bias terms -> softmax routing -> coef[8] per (n,c) ------
__global__ __launch_bounds__(64) void routing_k(const float* __restrict__ Mfull,
                                                const float* __restrict__ h2,
                                                const float* __restrict__ sq,
                                                const float* __restrict__ rowsum,
                                                const float* __restrict__ wA,
                                                const float* __restrict__ bA,
                                                float* __restrict__ coefb) {
    __shared__ float s0s[64], s1s[64], Ts[64], invs[64];
    int n = blockIdx.x;
    int c = threadIdx.x;
    {
        int a = c;
        s0s[a] = h2[((size_t)n * 64 + a) * L_LEN + 0];
        s1s[a] = h2[((size_t)n * 64 + a) * L_LEN + (L_LEN - 1)];
        Ts[a]  = rowsum[n * 64 + a];
        invs[a] = 1.f / (1.f + sq[n * 64 + a]);
    }
    float wreg[24];
#pragma unroll
    for (int q = 0; q < 24; ++q) wreg[q] = wA[c * 24 + q];
    float bc = bA[c];
    __syncthreads();
    float SG[8];
#pragma unroll
    for (int i = 0; i < 8; ++i) {
        float s = 0.f;
#pragma unroll
        for (int p = 0; p < 8; ++p) {
            int a = 8 * i + p;
            float Ta = Ts[a];
            s += invs[a] * (wreg[p * 3 + 0] * (Ta - s1s[a]) +
                            wreg[p * 3 + 1] * Ta +
                            wreg[p * 3 + 2] * (Ta - s0s[a]));
        }
        SG[i] = s;
    }
    float M[36];
    {
        const float* mp = Mfull + ((size_t)n * 64 + c) * 36;
        int k2 = 0;
#pragma unroll
        for (int i = 0; i < 8; ++i)
#pragma unroll
            for (int j = i; j < 8; ++j, ++k2)
                M[k2] = mp[k2] + bc * (SG[i] + SG[j]) + 4500.f * bc * bc;
    }
    float rs[8];
#pragma unroll
    for (int i = 0; i < 8; ++i) rs[i] = 0.f;
    {
        int idx2 = 0;
#pragma unroll
        for (int i = 0; i < 8; ++i)
#pragma unroll
            for (int j = i; j < 8; ++j, ++idx2) {
                rs[i] += M[idx2];
                if (j > i) rs[j] += M[idx2];
            }
    }
    float sumAll = 0.f;
#pragma unroll
    for (int i = 0; i < 8; ++i) sumAll += rs[i];
    float sqn1 = sumAll * (1.f / 64.f);
    float binv = 1.f / (8.f * (1.f + sqn1));
    float bv[8], mx = -1e30f;
#pragma unroll
    for (int i = 0; i < 8; ++i) { bv[i] = rs[i] * binv; mx = fmaxf(mx, bv[i]); }
    float e[8], se = 0.f;
#pragma unroll
    for (int i = 0; i < 8; ++i) { e[i] = expf(bv[i] - mx); se += e[i]; }
    float sinv = 1.f / se;
    float ci_[8];
#pragma unroll
    for (int i = 0; i < 8; ++i) ci_[i] = e[i] * sinv;
    float sqn2 = 0.f;
    {
        int idx2 = 0;
#pragma unroll
        for (int i = 0; i < 8; ++i)
#pragma unroll
            for (int j = i; j < 8; ++j, ++idx2)
                sqn2 += ((j > i) ? 2.f : 1.f) * ci_[i] * ci_[j] * M[idx2];
    }
    float scale = 1.f / (1.f + sqn2);
#pragma unroll
    for (int i = 0; i < 8; ++i) coefb[((size_t)n * 64 + c) * 8 + i] = ci_[i] * scale;
}

// -------- weff_k: WeffT[n][a][g][c] = coef[n,c,a>>3]*W[c,a&7,g]*inv[n,a] ------
__global__ __launch_bounds__(256) void weff_k(const float* __restrict__ coefb,
                                              const float* __restrict__ wA,
                                              const float* __restrict__ sq,
                                              const float* __restrict__ bA,
                                              float* __restrict__ WeffT,
                                              float* __restrict__ vbias) {
    int n = blockIdx.x;
    for (int idx = threadIdx.x; idx < 12288; idx += 256) {
        int a = idx / 192;
        int r = idx - 192 * a;
        int g = r >> 6;
        int c = r & 63;
        float inv = 1.f / (1.f + sq[n * 64 + a]);
        WeffT[(size_t)n * 12288 + idx] =
            coefb[((size_t)n * 64 + c) * 8 + (a >> 3)] * wA[c * 24 + (a & 7) * 3 + g] * inv;
    }
    if (threadIdx.x < 64) {
        float s = 0.f;
#pragma unroll
        for (int i = 0; i < 8; ++i) s += coefb[((size_t)n * 64 + threadIdx.x) * 8 + i];
        vbias[n * 64 + threadIdx.x] = bA[threadIdx.x] * s;
    }
}

// ---- outconv_k: out = Weff (64->64, k=3) * h2 + vbias, register-tiled GEMM ---
__global__ __launch_bounds__(256) void outconv_k(const float* __restrict__ h2,
                                                 const float* __restrict__ WeffT,
                                                 const float* __restrict__ vbias,
                                                 float* __restrict__ out) {
    __shared__ __align__(16) float hs[64 * 132];
    int n = blockIdx.x / NT2;
    int t = blockIdx.x - n * NT2;
    int l0 = t * T2;
    const float* h2n = h2 + (size_t)n * 64 * L_LEN;
    for (int idx = threadIdx.x; idx < 64 * 130; idx += 256) {
        int ci = idx / 130;
        int j = idx - ci * 130;
        int l = l0 - 1 + j;
        hs[ci * 132 + j] = (l >= 0 && l < L_LEN) ? h2n[(size_t)ci * L_LEN + l] : 0.f;
    }
    __syncthreads();
    int ta = threadIdx.x & 15;
    int tb = threadIdx.x >> 4;
    int k0 = ta * 4;
    int lt = tb * 8;
    float acc[4][8];
#pragma unroll
    for (int kq = 0; kq < 4; ++kq)
#pragma unroll
        for (int m = 0; m < 8; ++m) acc[kq][m] = 0.f;
    const float* wbase = WeffT + (size_t)n * 12288 + k0;
    for (int ci = 0; ci < 64; ++ci) {
        const float* hrow = &hs[ci * 132 + lt];
        float4 wa = *(const float4*)hrow;
        float4 wb = *(const float4*)(hrow + 4);
        float4 wc = *(const float4*)(hrow + 8);
        float win[12] = {wa.x, wa.y, wa.z, wa.w, wb.x, wb.y, wb.z, wb.w,
                         wc.x, wc.y, wc.z, wc.w};
        const float* wp = wbase + ci * 192;
#pragma unroll
        for (int g = 0; g < 3; ++g) {
            float4 wv = *(const float4*)(wp + g * 64);
#pragma unroll
            for (int m = 0; m < 8; ++m) {
                acc[0][m] += wv.x * win[m + g];
                acc[1][m] += wv.y * win[m + g];
                acc[2][m] += wv.z * win[m + g];
                acc[3][m] += wv.w * win[m + g];
            }
        }
    }
    int lbase = l0 + lt;
#pragma unroll
    for (int kq = 0; kq < 4; ++kq) {
        float vb = vbias[n * 64 + k0 + kq];
        float* orow = out + ((size_t)n * 64 + k0 + kq) * L_LEN + lbase;
        if (lbase < L_LEN) {
            float4 s0 = {acc[kq][0] + vb, acc[kq][1] + vb, acc[kq][2] + vb, acc[kq][3] + vb};
            *(float4*)orow = s0;
        }
        if (lbase + 4 < L_LEN) {
            float4 s1 = {acc[kq][4] + vb, acc[kq][5] + vb, acc[kq][6] + vb, acc[kq][7] + vb};
            *(float4*)(orow + 4) = s1;
        }
    }
}

extern "C" void kernel_launch(void* const* d_in, const int* in_sizes, int n_in,
                              void* d_out, int out_size, void* d_ws, size_t ws_size,
                              hipStream_t stream) {
    const float* x  = (const float*)d_in[0];
    const float* w1 = (const float*)d_in[1];
    const float* w2 = (const float*)d_in[2];
    const float* wA = (const float*)d_in[3];
    const float* bA = (const float*)d_in[4];
    float* out = (float*)d_out;
    char* ws = (char*)d_ws;
    const size_t HB = (size_t)64 * 64 * L_LEN * 4;   // 73,728,000 B
    float* h2     = (float*)(ws + HB);
    float* sq     = (float*)(ws + 2 * HB);            // 16 KB
    float* rowsum = (float*)(ws + 2 * HB + 16384);    // 16 KB
    float* w2t    = (float*)(ws + 2 * HB + 32768);    // 80 KB
    // overlays in the first HB region:
    float* Rp    = (float*)ws;                        // 62,914,560 B
    float* Rsum  = (float*)(ws + 62914560);           //  5,242,880 B
    float* Mfull = (float*)(ws + 68157440);           //    589,824 B
    float* coefb = (float*)(ws + 68747264);           //    131,072 B
    float* WeffT = (float*)(ws + 68878336);           //  3,145,728 B
    float* vbias = (float*)(ws + 72024064);           //     16,384 B

    hipMemsetAsync(sq, 0, 32768, stream);             // sq + rowsum
    prep_w2t_k<<<80, 256, 0, stream>>>(w2, w2t);
    conv12_k<<<64 * NT2, 256, 0, stream>>>(x, w1, w2t, h2, sq, rowsum);
    corr_k<<<64 * 2 * CKSPL, 256, 0, stream>>>(h2, Rp);
    reduce_k<<<64 * 80, 256, 0, stream>>>(Rp, Rsum);
    massemble_k<<<64 * 36, 256, 0, stream>>>(Rsum, h2, sq, wA, Mfull);
    routing_k<<<64, 64, 0, stream>>>(Mfull, h2, sq, rowsum, wA, bA, coefb);
    weff_k<<<64, 256, 0, stream>>>(coefb, wA, sq, bA, WeffT, vbias);
    outconv_k<<<64 * NT2, 256, 0, stream>>>(h2, WeffT, vbias, out);
}